// Round 3
// baseline (2283.335 us; speedup 1.0000x reference)
//
#include <hip/hip_runtime.h>
#include <math.h>

#define SLOPE 0.01f

__device__ __forceinline__ float lrelu(float v) { return v >= 0.f ? v : SLOPE * v; }

// ---------------------------------------------------------------------------
// GRU step (h0=0) for both layers, regenerate GCN weights, fold Wout/bout.
// ---------------------------------------------------------------------------
__global__ void prep_k(const float* __restrict__ m1, const float* __restrict__ Wih1,
                       const float* __restrict__ bih1, const float* __restrict__ bhh1,
                       const float* __restrict__ m2, const float* __restrict__ Wih2,
                       const float* __restrict__ bih2, const float* __restrict__ bhh2,
                       const float* __restrict__ wtW1, const float* __restrict__ wtb1,
                       const float* __restrict__ wtW2, const float* __restrict__ wtb2,
                       const float* __restrict__ Wout, const float* __restrict__ bout,
                       float* __restrict__ Wn1, float* __restrict__ Wn2,
                       float* __restrict__ wsum, float* __restrict__ bsum) {
    __shared__ float nm[32];   // new_mem1 [0..15], new_mem2 [16..31]
    int t = threadIdx.x;
    if (t < 32) {
        int L = t >> 4, j = t & 15;
        const float* m   = L ? m2   : m1;
        const float* Wih = L ? Wih2 : Wih1;
        const float* bih = L ? bih2 : bih1;
        const float* bhh = L ? bhh2 : bhh1;
        float gr = bih[j], gz = bih[16 + j], gn = bih[32 + j];
        for (int k = 0; k < 16; ++k) {
            float mk = m[k];
            gr += Wih[j * 16 + k] * mk;
            gz += Wih[(16 + j) * 16 + k] * mk;
            gn += Wih[(32 + j) * 16 + k] * mk;
        }
        float r = 1.f / (1.f + expf(-(gr + bhh[j])));
        float z = 1.f / (1.f + expf(-(gz + bhh[16 + j])));
        float n = tanhf(gn + r * bhh[32 + j]);
        nm[t] = (1.f - z) * n;          // + z*h, h==0
    }
    __syncthreads();
    float s1 = wtb1[t], s2 = wtb2[t];
    for (int k = 0; k < 16; ++k) {
        s1 += wtW1[t * 16 + k] * nm[k];
        s2 += wtW2[t * 16 + k] * nm[16 + k];
    }
    Wn1[t] = s1;
    Wn2[t] = s2;
    if (t < 16) wsum[t] = Wout[t] + Wout[16 + t];
    if (t == 0) bsum[0] = bout[0] + bout[1];
}

// ---------------------------------------------------------------------------
// CSR build: zero -> histogram -> 3-pass scan -> fill (srcs only)
// ---------------------------------------------------------------------------
__global__ void zero_k(int* __restrict__ cnt, int N) {
    int i = blockIdx.x * 256 + threadIdx.x;
    if (i < N) cnt[i] = 0;
}

__global__ void hist_k(int* __restrict__ cnt, const int* __restrict__ col, int E) {
    int e = blockIdx.x * 256 + threadIdx.x;
    if (e < E) atomicAdd(cnt + col[e], 1);
}

// pass A: per-block sum of 256 counts
__global__ void sred_k(const int* __restrict__ cnt, int* __restrict__ bred, int N) {
    __shared__ int s[4];
    int i = blockIdx.x * 256 + threadIdx.x;
    int v = (i < N) ? cnt[i] : 0;
#pragma unroll
    for (int m = 1; m < 64; m <<= 1) v += __shfl_xor(v, m);
    if ((threadIdx.x & 63) == 0) s[threadIdx.x >> 6] = v;
    __syncthreads();
    if (threadIdx.x == 0) bred[blockIdx.x] = s[0] + s[1] + s[2] + s[3];
}

// pass B: single-block exclusive scan of block sums (NB <= 512)
__global__ __launch_bounds__(512) void sscan_k(const int* __restrict__ bred,
                                               int* __restrict__ bscan,
                                               int* __restrict__ off,
                                               int NB, int N, int E) {
    __shared__ int s[512];
    int t = threadIdx.x;
    int v = (t < NB) ? bred[t] : 0;
    s[t] = v;
    __syncthreads();
    for (int d = 1; d < 512; d <<= 1) {
        int u = (t >= d) ? s[t - d] : 0;
        __syncthreads();
        s[t] += u;
        __syncthreads();
    }
    if (t < NB) bscan[t] = s[t] - v;   // exclusive
    if (t == 0) off[N] = E;
}

// pass C: per-block exclusive scan + apply; also cur and dis
__global__ void sfin_k(const int* __restrict__ cnt, const int* __restrict__ bscan,
                       int* __restrict__ off, int* __restrict__ cur,
                       float* __restrict__ dis, int N) {
    __shared__ int s[256];
    int t = threadIdx.x;
    int i = blockIdx.x * 256 + t;
    int v = (i < N) ? cnt[i] : 0;
    s[t] = v;
    __syncthreads();
    for (int d = 1; d < 256; d <<= 1) {
        int u = (t >= d) ? s[t - d] : 0;
        __syncthreads();
        s[t] += u;
        __syncthreads();
    }
    int ex = s[t] - v + bscan[blockIdx.x];
    if (i < N) {
        off[i] = ex;
        cur[i] = ex;
        dis[i] = rsqrtf((float)(v + 1));   // in-degree + self-loop
    }
}

__global__ void fill_k(const int* __restrict__ row, const int* __restrict__ col,
                       int* __restrict__ cur, int* __restrict__ srcs, int E) {
    int e = blockIdx.x * 256 + threadIdx.x;
    if (e >= E) return;
    int pos = atomicAdd(cur + col[e], 1);
    srcs[pos] = row[e];
}

// ---------------------------------------------------------------------------
// Fused MLP: xl1S = dis * (leaky(leaky(x@W1^T+b1)@W2^T+b2) @ Wn1^T)
// 64 nodes/block in LDS (transposed), 4 waves own 64-hu quarters each,
// wave-uniform W1/W2 offsets (readfirstlane) -> scalar-load broadcast.
// ---------------------------------------------------------------------------
__global__ __launch_bounds__(256, 3) void mlp_k(
        const float* __restrict__ x, const float* __restrict__ W1,
        const float* __restrict__ b1, const float* __restrict__ W2,
        const float* __restrict__ b2, const float* __restrict__ Wn1,
        const float* __restrict__ dis, float* __restrict__ xl, int N) {
    __shared__ float xs[128 * 64];       // xs[k*64+n]; reused as h2s[n*17+j]
    __shared__ float part[4 * 64 * 17];  // part[(q*64+n)*17+j]
    const int t    = threadIdx.x;
    const int nl   = t & 63;
    const int q    = __builtin_amdgcn_readfirstlane(t >> 6);  // wave-uniform
    const int node = blockIdx.x * 64 + nl;

    // ---- stage x tile (transposed, conflict-free) ----
    if (node < N) {
        const float4* xr = (const float4*)(x + (size_t)node * 128) + q * 8;
#pragma unroll
        for (int kk = 0; kk < 8; ++kk) {
            float4 v = xr[kk];
            int k = q * 32 + kk * 4;
            xs[(k + 0) * 64 + nl] = v.x;
            xs[(k + 1) * 64 + nl] = v.y;
            xs[(k + 2) * 64 + nl] = v.z;
            xs[(k + 3) * 64 + nl] = v.w;
        }
    } else {
#pragma unroll
        for (int kk = 0; kk < 32; ++kk) xs[(q * 32 + kk) * 64 + nl] = 0.f;
    }
    __syncthreads();

    // ---- stage 1+2: this wave's 64 hu values, 8 at a time ----
    float acc2[16];
#pragma unroll
    for (int j = 0; j < 16; ++j) acc2[j] = 0.f;
    for (int hh = 0; hh < 64; hh += 8) {
        const int hu0 = q * 64 + hh;
        const float* wb = W1 + (size_t)hu0 * 128;
        float a[8];
#pragma unroll
        for (int r = 0; r < 8; ++r) a[r] = 0.f;
        for (int kc = 0; kc < 128; kc += 16) {
            float xv[16];
#pragma unroll
            for (int kk = 0; kk < 16; ++kk) xv[kk] = xs[(kc + kk) * 64 + nl];
#pragma unroll
            for (int r = 0; r < 8; ++r)
#pragma unroll
                for (int kk = 0; kk < 16; ++kk)
                    a[r] = fmaf(wb[r * 128 + kc + kk], xv[kk], a[r]);
        }
#pragma unroll
        for (int r = 0; r < 8; ++r) {
            float h1 = lrelu(a[r] + b1[hu0 + r]);
#pragma unroll
            for (int j = 0; j < 16; ++j)
                acc2[j] = fmaf(W2[j * 256 + hu0 + r], h1, acc2[j]);
        }
    }
#pragma unroll
    for (int j = 0; j < 16; ++j) part[(q * 64 + nl) * 17 + j] = acc2[j];
    __syncthreads();

    // ---- h2 = lrelu(sum over quarters + b2) -> reuse xs as h2s[n*17+j] ----
    {
        const int j0 = q * 4;
#pragma unroll
        for (int jj = 0; jj < 4; ++jj) {
            int j = j0 + jj;
            float s = b2[j];
#pragma unroll
            for (int qq = 0; qq < 4; ++qq) s += part[(qq * 64 + nl) * 17 + j];
            xs[nl * 17 + j] = lrelu(s);
        }
    }
    __syncthreads();

    // ---- stage 3: o = h2 @ Wn1^T, scaled by dis ----
    {
        const int c0 = q * 4;
        float o[4];
#pragma unroll
        for (int cc = 0; cc < 4; ++cc) {
            float s = 0.f;
#pragma unroll
            for (int j = 0; j < 16; ++j)
                s = fmaf(Wn1[(c0 + cc) * 16 + j], xs[nl * 17 + j], s);
            o[cc] = s;
        }
        if (node < N) {
            float d = dis[node];
            float4* xo = (float4*)(xl + (size_t)node * 16 + c0);
            *xo = make_float4(d * o[0], d * o[1], d * o[2], d * o[3]);
        }
    }
}

// ---------------------------------------------------------------------------
// Gather layer 1 (wave per node, 4 edges x 16 channels in flight):
// inner = xinS[n] + sum_e xinS[srcs[e]];  agg = bias + dis[n]*inner
// xoutS = dis[n] * (leaky(agg) @ Wn2^T)
// ---------------------------------------------------------------------------
__global__ void gather1_k(const int* __restrict__ off, const int* __restrict__ srcs,
                          const float* __restrict__ dis, const float* __restrict__ xin,
                          const float* __restrict__ bias, const float* __restrict__ Wn2,
                          float* __restrict__ xout, int N) {
    __shared__ float w[256];             // transposed: w[j*16+c] = Wn2[c*16+j]
    {
        int j = threadIdx.x >> 4, c = threadIdx.x & 15;
        w[threadIdx.x] = Wn2[c * 16 + j];
    }
    __syncthreads();
    int t = blockIdx.x * 256 + threadIdx.x;
    int n = t >> 6;
    if (n >= N) return;
    int lane = t & 63, sub = lane >> 4, c = lane & 15;
    float acc = (sub == 0) ? xin[(size_t)n * 16 + c] : 0.f;   // self term
    int e1 = off[n + 1];
    for (int e = off[n] + sub; e < e1; e += 4)
        acc += xin[(size_t)srcs[e] * 16 + c];
    acc += __shfl_xor(acc, 16);
    acc += __shfl_xor(acc, 32);
    float d = dis[n];
    float h = lrelu(fmaf(d, acc, bias[c]));
    float o = 0.f;
#pragma unroll
    for (int j = 0; j < 16; ++j) o = fmaf(w[j * 16 + c], __shfl(h, j, 16), o);
    if (sub == 0) xout[(size_t)n * 16 + c] = d * o;
}

// ---------------------------------------------------------------------------
// Gather layer 2 + final projection: out[n] = bsum + sum_c wsum[c]*leaky(agg_c)
// ---------------------------------------------------------------------------
__global__ void gather2_k(const int* __restrict__ off, const int* __restrict__ srcs,
                          const float* __restrict__ dis, const float* __restrict__ xin,
                          const float* __restrict__ bias, const float* __restrict__ wsum,
                          const float* __restrict__ bsum, float* __restrict__ out, int N) {
    int t = blockIdx.x * 256 + threadIdx.x;
    int n = t >> 6;
    if (n >= N) return;
    int lane = t & 63, sub = lane >> 4, c = lane & 15;
    float acc = (sub == 0) ? xin[(size_t)n * 16 + c] : 0.f;
    int e1 = off[n + 1];
    for (int e = off[n] + sub; e < e1; e += 4)
        acc += xin[(size_t)srcs[e] * 16 + c];
    acc += __shfl_xor(acc, 16);
    acc += __shfl_xor(acc, 32);
    float v = wsum[c] * lrelu(fmaf(dis[n], acc, bias[c]));
#pragma unroll
    for (int m = 1; m < 16; m <<= 1) v += __shfl_xor(v, m);
    if (lane == 0) out[n] = v + bsum[0];
}

// ---------------------------------------------------------------------------
extern "C" void kernel_launch(void* const* d_in, const int* in_sizes, int n_in,
                              void* d_out, int out_size, void* d_ws, size_t ws_size,
                              hipStream_t stream) {
    const float* x      = (const float*)d_in[0];
    const int*   edge   = (const int*)d_in[1];
    const float* W1     = (const float*)d_in[2];
    const float* b1     = (const float*)d_in[3];
    const float* W2     = (const float*)d_in[4];
    const float* b2     = (const float*)d_in[5];
    const float* mem1   = (const float*)d_in[6];
    const float* g1_Wih = (const float*)d_in[7];
    const float* g1_bih = (const float*)d_in[9];
    const float* g1_bhh = (const float*)d_in[10];
    const float* wt1_W  = (const float*)d_in[11];
    const float* wt1_b  = (const float*)d_in[12];
    const float* gcn1_b = (const float*)d_in[13];
    const float* mem2   = (const float*)d_in[14];
    const float* g2_Wih = (const float*)d_in[15];
    const float* g2_bih = (const float*)d_in[17];
    const float* g2_bhh = (const float*)d_in[18];
    const float* wt2_W  = (const float*)d_in[19];
    const float* wt2_b  = (const float*)d_in[20];
    const float* gcn2_b = (const float*)d_in[21];
    const float* Wout   = (const float*)d_in[22];
    const float* bout   = (const float*)d_in[23];
    float* out = (float*)d_out;

    const int N = in_sizes[0] / 128;
    const int E = in_sizes[1] / 2;
    const int* row = edge;
    const int* col = edge + E;

    const int gN  = (N + 255) / 256;       // blocks over nodes
    const int gE  = (E + 255) / 256;       // blocks over edges
    const int gM  = (N + 63) / 64;         // mlp blocks (64 nodes each)
    const int gG  = (N * 64 + 255) / 256;  // gather blocks (wave per node)
    const int NB  = gN;                    // scan block count (<=512)

    float* ws    = (float*)d_ws;
    float* bufA  = ws;                        // [N*16] xl1 (dis-scaled)
    float* bufB  = bufA + (size_t)N * 16;     // [N*16] xl2 (dis-scaled)
    float* dis   = bufB + (size_t)N * 16;     // [N]
    float* sm    = dis + N;                   // smalls
    float* Wn1   = sm;
    float* Wn2   = sm + 256;
    float* wsum  = sm + 512;
    float* bsum  = sm + 528;
    int*   cnt   = (int*)(sm + 544);          // [N]
    int*   off   = cnt + N;                   // [N+1]
    int*   cur   = off + N + 1;               // [N]
    int*   bred  = cur + N;                   // [NB]
    int*   bscan = bred + NB;                 // [NB]
    int*   srcs  = bscan + NB;                // [E]

    prep_k<<<1, 256, 0, stream>>>(mem1, g1_Wih, g1_bih, g1_bhh,
                                  mem2, g2_Wih, g2_bih, g2_bhh,
                                  wt1_W, wt1_b, wt2_W, wt2_b,
                                  Wout, bout, Wn1, Wn2, wsum, bsum);
    zero_k<<<gN, 256, 0, stream>>>(cnt, N);
    hist_k<<<gE, 256, 0, stream>>>(cnt, col, E);
    sred_k<<<gN, 256, 0, stream>>>(cnt, bred, N);
    sscan_k<<<1, 512, 0, stream>>>(bred, bscan, off, NB, N, E);
    sfin_k<<<gN, 256, 0, stream>>>(cnt, bscan, off, cur, dis, N);
    fill_k<<<gE, 256, 0, stream>>>(row, col, cur, srcs, E);
    mlp_k<<<gM, 256, 0, stream>>>(x, W1, b1, W2, b2, Wn1, dis, bufA, N);
    gather1_k<<<gG, 256, 0, stream>>>(off, srcs, dis, bufA, gcn1_b, Wn2, bufB, N);
    gather2_k<<<gG, 256, 0, stream>>>(off, srcs, dis, bufB, gcn2_b, wsum, bsum, out, N);
}

// Round 4
// 912.324 us; speedup vs baseline: 2.5028x; 2.5028x over previous
//
#include <hip/hip_runtime.h>
#include <math.h>

#define SLOPE 0.01f

__device__ __forceinline__ float lrelu(float v) { return v >= 0.f ? v : SLOPE * v; }

// ---------------------------------------------------------------------------
// GRU step (h0=0) for both layers, regenerate GCN weights, fold Wout/bout.
// ---------------------------------------------------------------------------
__global__ void prep_k(const float* __restrict__ m1, const float* __restrict__ Wih1,
                       const float* __restrict__ bih1, const float* __restrict__ bhh1,
                       const float* __restrict__ m2, const float* __restrict__ Wih2,
                       const float* __restrict__ bih2, const float* __restrict__ bhh2,
                       const float* __restrict__ wtW1, const float* __restrict__ wtb1,
                       const float* __restrict__ wtW2, const float* __restrict__ wtb2,
                       const float* __restrict__ Wout, const float* __restrict__ bout,
                       float* __restrict__ Wn1, float* __restrict__ Wn2,
                       float* __restrict__ wsum, float* __restrict__ bsum) {
    __shared__ float nm[32];   // new_mem1 [0..15], new_mem2 [16..31]
    int t = threadIdx.x;
    if (t < 32) {
        int L = t >> 4, j = t & 15;
        const float* m   = L ? m2   : m1;
        const float* Wih = L ? Wih2 : Wih1;
        const float* bih = L ? bih2 : bih1;
        const float* bhh = L ? bhh2 : bhh1;
        float gr = bih[j], gz = bih[16 + j], gn = bih[32 + j];
        for (int k = 0; k < 16; ++k) {
            float mk = m[k];
            gr += Wih[j * 16 + k] * mk;
            gz += Wih[(16 + j) * 16 + k] * mk;
            gn += Wih[(32 + j) * 16 + k] * mk;
        }
        float r = 1.f / (1.f + expf(-(gr + bhh[j])));
        float z = 1.f / (1.f + expf(-(gz + bhh[16 + j])));
        float n = tanhf(gn + r * bhh[32 + j]);
        nm[t] = (1.f - z) * n;          // + z*h, h==0
    }
    __syncthreads();
    float s1 = wtb1[t], s2 = wtb2[t];
    for (int k = 0; k < 16; ++k) {
        s1 += wtW1[t * 16 + k] * nm[k];
        s2 += wtW2[t * 16 + k] * nm[16 + k];
    }
    Wn1[t] = s1;
    Wn2[t] = s2;
    if (t < 16) wsum[t] = Wout[t] + Wout[16 + t];
    if (t == 0) bsum[0] = bout[0] + bout[1];
}

// ---------------------------------------------------------------------------
// CSR build: zero -> histogram -> 3-pass scan -> fill (srcs only)
// ---------------------------------------------------------------------------
__global__ void zero_k(int* __restrict__ cnt, int N) {
    int i = blockIdx.x * 256 + threadIdx.x;
    if (i < N) cnt[i] = 0;
}

__global__ void hist_k(int* __restrict__ cnt, const int* __restrict__ col, int E) {
    int e = blockIdx.x * 256 + threadIdx.x;
    if (e < E) atomicAdd(cnt + col[e], 1);
}

// pass A: per-block sum of 256 counts
__global__ void sred_k(const int* __restrict__ cnt, int* __restrict__ bred, int N) {
    __shared__ int s[4];
    int i = blockIdx.x * 256 + threadIdx.x;
    int v = (i < N) ? cnt[i] : 0;
#pragma unroll
    for (int m = 1; m < 64; m <<= 1) v += __shfl_xor(v, m);
    if ((threadIdx.x & 63) == 0) s[threadIdx.x >> 6] = v;
    __syncthreads();
    if (threadIdx.x == 0) bred[blockIdx.x] = s[0] + s[1] + s[2] + s[3];
}

// pass B: single-block exclusive scan of block sums (NB <= 512)
__global__ __launch_bounds__(512) void sscan_k(const int* __restrict__ bred,
                                               int* __restrict__ bscan,
                                               int* __restrict__ off,
                                               int NB, int N, int E) {
    __shared__ int s[512];
    int t = threadIdx.x;
    int v = (t < NB) ? bred[t] : 0;
    s[t] = v;
    __syncthreads();
    for (int d = 1; d < 512; d <<= 1) {
        int u = (t >= d) ? s[t - d] : 0;
        __syncthreads();
        s[t] += u;
        __syncthreads();
    }
    if (t < NB) bscan[t] = s[t] - v;   // exclusive
    if (t == 0) off[N] = E;
}

// pass C: per-block exclusive scan + apply; also cur and dis
__global__ void sfin_k(const int* __restrict__ cnt, const int* __restrict__ bscan,
                       int* __restrict__ off, int* __restrict__ cur,
                       float* __restrict__ dis, int N) {
    __shared__ int s[256];
    int t = threadIdx.x;
    int i = blockIdx.x * 256 + t;
    int v = (i < N) ? cnt[i] : 0;
    s[t] = v;
    __syncthreads();
    for (int d = 1; d < 256; d <<= 1) {
        int u = (t >= d) ? s[t - d] : 0;
        __syncthreads();
        s[t] += u;
        __syncthreads();
    }
    int ex = s[t] - v + bscan[blockIdx.x];
    if (i < N) {
        off[i] = ex;
        cur[i] = ex;
        dis[i] = rsqrtf((float)(v + 1));   // in-degree + self-loop
    }
}

__global__ void fill_k(const int* __restrict__ row, const int* __restrict__ col,
                       int* __restrict__ cur, int* __restrict__ srcs, int E) {
    int e = blockIdx.x * 256 + threadIdx.x;
    if (e >= E) return;
    int pos = atomicAdd(cur + col[e], 1);
    srcs[pos] = row[e];
}

// ---------------------------------------------------------------------------
// Fused MLP: xl1S = dis * (leaky(leaky(x@W1^T+b1)@W2^T+b2) @ Wn1^T)
// 64 nodes/block in LDS (transposed), 4 waves own 64-hu quarters each,
// wave-uniform W1/W2 offsets (readfirstlane) -> scalar-load broadcast.
// Inner loop deliberately simple (1 ds_read + 8 FMA per k): the R3 register-
// batched variant spilled to scratch (FETCH 4 GB, WRITE 459 MB) -> 6x slower.
// ---------------------------------------------------------------------------
__global__ __launch_bounds__(256, 3) void mlp_k(
        const float* __restrict__ x, const float* __restrict__ W1,
        const float* __restrict__ b1, const float* __restrict__ W2,
        const float* __restrict__ b2, const float* __restrict__ Wn1,
        const float* __restrict__ dis, float* __restrict__ xl, int N) {
    __shared__ float xs[128 * 64];       // xs[k*64+n]; reused as h2s[n*17+j]
    __shared__ float part[4 * 64 * 17];  // part[(q*64+n)*17+j]
    const int t    = threadIdx.x;
    const int nl   = t & 63;
    const int q    = __builtin_amdgcn_readfirstlane(t >> 6);  // wave-uniform
    const int node = blockIdx.x * 64 + nl;

    // ---- stage x tile (transposed, conflict-free) ----
    if (node < N) {
        const float4* xr = (const float4*)(x + (size_t)node * 128) + q * 8;
#pragma unroll
        for (int kk = 0; kk < 8; ++kk) {
            float4 v = xr[kk];
            int k = q * 32 + kk * 4;
            xs[(k + 0) * 64 + nl] = v.x;
            xs[(k + 1) * 64 + nl] = v.y;
            xs[(k + 2) * 64 + nl] = v.z;
            xs[(k + 3) * 64 + nl] = v.w;
        }
    } else {
#pragma unroll
        for (int kk = 0; kk < 32; ++kk) xs[(q * 32 + kk) * 64 + nl] = 0.f;
    }
    __syncthreads();

    // ---- stage 1+2: this wave's 64 hu values, 8 at a time ----
    float acc2[16];
#pragma unroll
    for (int j = 0; j < 16; ++j) acc2[j] = 0.f;
    for (int hh = 0; hh < 64; hh += 8) {
        const int hu0 = q * 64 + hh;
        const float* wb = W1 + (size_t)hu0 * 128;
        float a[8];
#pragma unroll
        for (int r = 0; r < 8; ++r) a[r] = 0.f;
        for (int k = 0; k < 128; ++k) {
            float xv = xs[k * 64 + nl];
#pragma unroll
            for (int r = 0; r < 8; ++r) a[r] = fmaf(wb[r * 128 + k], xv, a[r]);
        }
#pragma unroll
        for (int r = 0; r < 8; ++r) {
            float h1 = lrelu(a[r] + b1[hu0 + r]);
#pragma unroll
            for (int j = 0; j < 16; ++j)
                acc2[j] = fmaf(W2[j * 256 + hu0 + r], h1, acc2[j]);
        }
    }
#pragma unroll
    for (int j = 0; j < 16; ++j) part[(q * 64 + nl) * 17 + j] = acc2[j];
    __syncthreads();

    // ---- h2 = lrelu(sum over quarters + b2) -> reuse xs as h2s[n*17+j] ----
    {
        const int j0 = q * 4;
#pragma unroll
        for (int jj = 0; jj < 4; ++jj) {
            int j = j0 + jj;
            float s = b2[j];
#pragma unroll
            for (int qq = 0; qq < 4; ++qq) s += part[(qq * 64 + nl) * 17 + j];
            xs[nl * 17 + j] = lrelu(s);
        }
    }
    __syncthreads();

    // ---- stage 3: o = h2 @ Wn1^T, scaled by dis ----
    {
        const int c0 = q * 4;
        float o[4];
#pragma unroll
        for (int cc = 0; cc < 4; ++cc) {
            float s = 0.f;
#pragma unroll
            for (int j = 0; j < 16; ++j)
                s = fmaf(Wn1[(c0 + cc) * 16 + j], xs[nl * 17 + j], s);
            o[cc] = s;
        }
        if (node < N) {
            float d = dis[node];
            float4* xo = (float4*)(xl + (size_t)node * 16 + c0);
            *xo = make_float4(d * o[0], d * o[1], d * o[2], d * o[3]);
        }
    }
}

// ---------------------------------------------------------------------------
// Gather layer 1 (wave per node, 4 edges x 16 channels in flight):
// inner = xinS[n] + sum_e xinS[srcs[e]];  agg = bias + dis[n]*inner
// xoutS = dis[n] * (leaky(agg) @ Wn2^T)
// ---------------------------------------------------------------------------
__global__ void gather1_k(const int* __restrict__ off, const int* __restrict__ srcs,
                          const float* __restrict__ dis, const float* __restrict__ xin,
                          const float* __restrict__ bias, const float* __restrict__ Wn2,
                          float* __restrict__ xout, int N) {
    __shared__ float w[256];             // transposed: w[j*16+c] = Wn2[c*16+j]
    {
        int j = threadIdx.x >> 4, c = threadIdx.x & 15;
        w[threadIdx.x] = Wn2[c * 16 + j];
    }
    __syncthreads();
    int t = blockIdx.x * 256 + threadIdx.x;
    int n = t >> 6;
    if (n >= N) return;
    int lane = t & 63, sub = lane >> 4, c = lane & 15;
    float acc = (sub == 0) ? xin[(size_t)n * 16 + c] : 0.f;   // self term
    int e1 = off[n + 1];
    for (int e = off[n] + sub; e < e1; e += 4)
        acc += xin[(size_t)srcs[e] * 16 + c];
    acc += __shfl_xor(acc, 16);
    acc += __shfl_xor(acc, 32);
    float d = dis[n];
    float h = lrelu(fmaf(d, acc, bias[c]));
    float o = 0.f;
#pragma unroll
    for (int j = 0; j < 16; ++j) o = fmaf(w[j * 16 + c], __shfl(h, j, 16), o);
    if (sub == 0) xout[(size_t)n * 16 + c] = d * o;
}

// ---------------------------------------------------------------------------
// Gather layer 2 + final projection: out[n] = bsum + sum_c wsum[c]*leaky(agg_c)
// ---------------------------------------------------------------------------
__global__ void gather2_k(const int* __restrict__ off, const int* __restrict__ srcs,
                          const float* __restrict__ dis, const float* __restrict__ xin,
                          const float* __restrict__ bias, const float* __restrict__ wsum,
                          const float* __restrict__ bsum, float* __restrict__ out, int N) {
    int t = blockIdx.x * 256 + threadIdx.x;
    int n = t >> 6;
    if (n >= N) return;
    int lane = t & 63, sub = lane >> 4, c = lane & 15;
    float acc = (sub == 0) ? xin[(size_t)n * 16 + c] : 0.f;
    int e1 = off[n + 1];
    for (int e = off[n] + sub; e < e1; e += 4)
        acc += xin[(size_t)srcs[e] * 16 + c];
    acc += __shfl_xor(acc, 16);
    acc += __shfl_xor(acc, 32);
    float v = wsum[c] * lrelu(fmaf(dis[n], acc, bias[c]));
#pragma unroll
    for (int m = 1; m < 16; m <<= 1) v += __shfl_xor(v, m);
    if (lane == 0) out[n] = v + bsum[0];
}

// ---------------------------------------------------------------------------
extern "C" void kernel_launch(void* const* d_in, const int* in_sizes, int n_in,
                              void* d_out, int out_size, void* d_ws, size_t ws_size,
                              hipStream_t stream) {
    const float* x      = (const float*)d_in[0];
    const int*   edge   = (const int*)d_in[1];
    const float* W1     = (const float*)d_in[2];
    const float* b1     = (const float*)d_in[3];
    const float* W2     = (const float*)d_in[4];
    const float* b2     = (const float*)d_in[5];
    const float* mem1   = (const float*)d_in[6];
    const float* g1_Wih = (const float*)d_in[7];
    const float* g1_bih = (const float*)d_in[9];
    const float* g1_bhh = (const float*)d_in[10];
    const float* wt1_W  = (const float*)d_in[11];
    const float* wt1_b  = (const float*)d_in[12];
    const float* gcn1_b = (const float*)d_in[13];
    const float* mem2   = (const float*)d_in[14];
    const float* g2_Wih = (const float*)d_in[15];
    const float* g2_bih = (const float*)d_in[17];
    const float* g2_bhh = (const float*)d_in[18];
    const float* wt2_W  = (const float*)d_in[19];
    const float* wt2_b  = (const float*)d_in[20];
    const float* gcn2_b = (const float*)d_in[21];
    const float* Wout   = (const float*)d_in[22];
    const float* bout   = (const float*)d_in[23];
    float* out = (float*)d_out;

    const int N = in_sizes[0] / 128;
    const int E = in_sizes[1] / 2;
    const int* row = edge;
    const int* col = edge + E;

    const int gN  = (N + 255) / 256;       // blocks over nodes
    const int gE  = (E + 255) / 256;       // blocks over edges
    const int gM  = (N + 63) / 64;         // mlp blocks (64 nodes each)
    const int gG  = (N * 64 + 255) / 256;  // gather blocks (wave per node)
    const int NB  = gN;                    // scan block count (<=512)

    float* ws    = (float*)d_ws;
    float* bufA  = ws;                        // [N*16] xl1 (dis-scaled)
    float* bufB  = bufA + (size_t)N * 16;     // [N*16] xl2 (dis-scaled)
    float* dis   = bufB + (size_t)N * 16;     // [N]
    float* sm    = dis + N;                   // smalls
    float* Wn1   = sm;
    float* Wn2   = sm + 256;
    float* wsum  = sm + 512;
    float* bsum  = sm + 528;
    int*   cnt   = (int*)(sm + 544);          // [N]
    int*   off   = cnt + N;                   // [N+1]
    int*   cur   = off + N + 1;               // [N]
    int*   bred  = cur + N;                   // [NB]
    int*   bscan = bred + NB;                 // [NB]
    int*   srcs  = bscan + NB;                // [E]

    prep_k<<<1, 256, 0, stream>>>(mem1, g1_Wih, g1_bih, g1_bhh,
                                  mem2, g2_Wih, g2_bih, g2_bhh,
                                  wt1_W, wt1_b, wt2_W, wt2_b,
                                  Wout, bout, Wn1, Wn2, wsum, bsum);
    zero_k<<<gN, 256, 0, stream>>>(cnt, N);
    hist_k<<<gE, 256, 0, stream>>>(cnt, col, E);
    sred_k<<<gN, 256, 0, stream>>>(cnt, bred, N);
    sscan_k<<<1, 512, 0, stream>>>(bred, bscan, off, NB, N, E);
    sfin_k<<<gN, 256, 0, stream>>>(cnt, bscan, off, cur, dis, N);
    fill_k<<<gE, 256, 0, stream>>>(row, col, cur, srcs, E);
    mlp_k<<<gM, 256, 0, stream>>>(x, W1, b1, W2, b2, Wn1, dis, bufA, N);
    gather1_k<<<gG, 256, 0, stream>>>(off, srcs, dis, bufA, gcn1_b, Wn2, bufB, N);
    gather2_k<<<gG, 256, 0, stream>>>(off, srcs, dis, bufB, gcn2_b, wsum, bsum, out, N);
}

// Round 5
// 813.811 us; speedup vs baseline: 2.8057x; 1.1211x over previous
//
#include <hip/hip_runtime.h>
#include <math.h>

#define SLOPE 0.01f
#define BSH  11          // destination bucket = dest >> 11  (2048 dests/bucket)
#define BMAX 64          // max buckets (N <= 131072)

__device__ __forceinline__ float lrelu(float v) { return v >= 0.f ? v : SLOPE * v; }

// ---------------------------------------------------------------------------
// GRU step (h0=0) for both layers, regenerate GCN weights, fold Wout/bout.
// ---------------------------------------------------------------------------
__global__ void prep_k(const float* __restrict__ m1, const float* __restrict__ Wih1,
                       const float* __restrict__ bih1, const float* __restrict__ bhh1,
                       const float* __restrict__ m2, const float* __restrict__ Wih2,
                       const float* __restrict__ bih2, const float* __restrict__ bhh2,
                       const float* __restrict__ wtW1, const float* __restrict__ wtb1,
                       const float* __restrict__ wtW2, const float* __restrict__ wtb2,
                       const float* __restrict__ Wout, const float* __restrict__ bout,
                       float* __restrict__ Wn1, float* __restrict__ Wn2,
                       float* __restrict__ wsum, float* __restrict__ bsum) {
    __shared__ float nm[32];   // new_mem1 [0..15], new_mem2 [16..31]
    int t = threadIdx.x;
    if (t < 32) {
        int L = t >> 4, j = t & 15;
        const float* m   = L ? m2   : m1;
        const float* Wih = L ? Wih2 : Wih1;
        const float* bih = L ? bih2 : bih1;
        const float* bhh = L ? bhh2 : bhh1;
        float gr = bih[j], gz = bih[16 + j], gn = bih[32 + j];
        for (int k = 0; k < 16; ++k) {
            float mk = m[k];
            gr += Wih[j * 16 + k] * mk;
            gz += Wih[(16 + j) * 16 + k] * mk;
            gn += Wih[(32 + j) * 16 + k] * mk;
        }
        float r = 1.f / (1.f + expf(-(gr + bhh[j])));
        float z = 1.f / (1.f + expf(-(gz + bhh[16 + j])));
        float n = tanhf(gn + r * bhh[32 + j]);
        nm[t] = (1.f - z) * n;          // + z*h, h==0
    }
    __syncthreads();
    float s1 = wtb1[t], s2 = wtb2[t];
    for (int k = 0; k < 16; ++k) {
        s1 += wtW1[t * 16 + k] * nm[k];
        s2 += wtW2[t * 16 + k] * nm[16 + k];
    }
    Wn1[t] = s1;
    Wn2[t] = s2;
    if (t < 16) wsum[t] = Wout[t] + Wout[16 + t];
    if (t == 0) bsum[0] = bout[0] + bout[1];
}

// ---------------------------------------------------------------------------
// CSR build: zero -> histogram -> 3-pass scan -> bucketed 2-pass fill
// ---------------------------------------------------------------------------
__global__ void zero_k(int* __restrict__ cnt, int N) {
    int i = blockIdx.x * 256 + threadIdx.x;
    if (i < N) cnt[i] = 0;
}

__global__ void hist_k(int* __restrict__ cnt, const int* __restrict__ col, int E) {
    int e = blockIdx.x * 256 + threadIdx.x;
    if (e < E) atomicAdd(cnt + col[e], 1);
}

// pass A: per-block sum of 256 counts
__global__ void sred_k(const int* __restrict__ cnt, int* __restrict__ bred, int N) {
    __shared__ int s[4];
    int i = blockIdx.x * 256 + threadIdx.x;
    int v = (i < N) ? cnt[i] : 0;
#pragma unroll
    for (int m = 1; m < 64; m <<= 1) v += __shfl_xor(v, m);
    if ((threadIdx.x & 63) == 0) s[threadIdx.x >> 6] = v;
    __syncthreads();
    if (threadIdx.x == 0) bred[blockIdx.x] = s[0] + s[1] + s[2] + s[3];
}

// pass B: single-block exclusive scan of block sums (NB <= 512)
__global__ __launch_bounds__(512) void sscan_k(const int* __restrict__ bred,
                                               int* __restrict__ bscan,
                                               int* __restrict__ off,
                                               int NB, int N, int E) {
    __shared__ int s[512];
    int t = threadIdx.x;
    int v = (t < NB) ? bred[t] : 0;
    s[t] = v;
    __syncthreads();
    for (int d = 1; d < 512; d <<= 1) {
        int u = (t >= d) ? s[t - d] : 0;
        __syncthreads();
        s[t] += u;
        __syncthreads();
    }
    if (t < NB) bscan[t] = s[t] - v;   // exclusive
    if (t == 0) off[N] = E;
}

// pass C: per-block exclusive scan + apply; also cur, dis, bucket bases
__global__ void sfin_k(const int* __restrict__ cnt, const int* __restrict__ bscan,
                       int* __restrict__ off, int* __restrict__ cur,
                       float* __restrict__ dis, int* __restrict__ bcur, int N) {
    __shared__ int s[256];
    int t = threadIdx.x;
    int i = blockIdx.x * 256 + t;
    int v = (i < N) ? cnt[i] : 0;
    s[t] = v;
    __syncthreads();
    for (int d = 1; d < 256; d <<= 1) {
        int u = (t >= d) ? s[t - d] : 0;
        __syncthreads();
        s[t] += u;
        __syncthreads();
    }
    int ex = s[t] - v + bscan[blockIdx.x];
    if (i < N) {
        off[i] = ex;
        cur[i] = ex;
        dis[i] = rsqrtf((float)(v + 1));   // in-degree + self-loop
        if ((i & ((1 << BSH) - 1)) == 0) bcur[i >> BSH] = ex;  // bucket base
    }
}

// fill pass 1: per-block LDS bucket counts -> chunk reservation -> dense
// append of (src,pos) into bucket-ordered stage. pos = final CSR slot.
__global__ void fill1_k(const int* __restrict__ row, const int* __restrict__ col,
                        int* __restrict__ cur, int* __restrict__ bcur,
                        int2* __restrict__ stage, int E) {
    __shared__ int lcnt[BMAX];
    __shared__ int lbase[BMAX];
    const int t = threadIdx.x;
    if (t < BMAX) lcnt[t] = 0;
    __syncthreads();
    const int base = blockIdx.x * 2048;
    int r[8], pos[8], pk[8];
#pragma unroll
    for (int i = 0; i < 8; ++i) {
        int e = base + i * 256 + t;
        if (e < E) {
            int d = col[e];
            int b = d >> BSH;
            int slot = atomicAdd(&lcnt[b], 1);
            r[i]   = row[e];
            pos[i] = atomicAdd(cur + d, 1);
            pk[i]  = (b << 16) | slot;
        } else pk[i] = -1;
    }
    __syncthreads();
    if (t < BMAX) lbase[t] = atomicAdd(bcur + t, lcnt[t]);
    __syncthreads();
#pragma unroll
    for (int i = 0; i < 8; ++i) {
        if (pk[i] >= 0) {
            int b = pk[i] >> 16, slot = pk[i] & 0xFFFF;
            stage[lbase[b] + slot] = make_int2(r[i], pos[i]);
        }
    }
}

// fill pass 2: stream stage coalesced, scatter into per-bucket srcs windows
__global__ void fill2_k(const int2* __restrict__ stage, int* __restrict__ srcs, int E) {
    int i0 = (blockIdx.x * 256 + threadIdx.x) * 2;
    if (i0 + 1 < E) {
        int4 v = *(const int4*)(stage + i0);   // 16B load (stage 16B-aligned)
        srcs[v.y] = v.x;
        srcs[v.w] = v.z;
    } else if (i0 < E) {
        int2 v = stage[i0];
        srcs[v.y] = v.x;
    }
}

// ---------------------------------------------------------------------------
// Fused MLP: xl1S = dis * (leaky(leaky(x@W1^T+b1)@W2^T+b2) @ Wn1^T)
// 64 nodes/block in LDS (transposed), 4 waves own 64-hu quarters each,
// wave-uniform W1/W2 offsets (readfirstlane) -> scalar-load broadcast.
// Inner loop deliberately simple (1 ds_read + 8 FMA per k): the R3 register-
// batched variant spilled to scratch (FETCH 4 GB, WRITE 459 MB) -> 6x slower.
// ---------------------------------------------------------------------------
__global__ __launch_bounds__(256, 3) void mlp_k(
        const float* __restrict__ x, const float* __restrict__ W1,
        const float* __restrict__ b1, const float* __restrict__ W2,
        const float* __restrict__ b2, const float* __restrict__ Wn1,
        const float* __restrict__ dis, float* __restrict__ xl, int N) {
    __shared__ float xs[128 * 64];       // xs[k*64+n]; reused as h2s[n*17+j]
    __shared__ float part[4 * 64 * 17];  // part[(q*64+n)*17+j]
    const int t    = threadIdx.x;
    const int nl   = t & 63;
    const int q    = __builtin_amdgcn_readfirstlane(t >> 6);  // wave-uniform
    const int node = blockIdx.x * 64 + nl;

    // ---- stage x tile (transposed, conflict-free) ----
    if (node < N) {
        const float4* xr = (const float4*)(x + (size_t)node * 128) + q * 8;
#pragma unroll
        for (int kk = 0; kk < 8; ++kk) {
            float4 v = xr[kk];
            int k = q * 32 + kk * 4;
            xs[(k + 0) * 64 + nl] = v.x;
            xs[(k + 1) * 64 + nl] = v.y;
            xs[(k + 2) * 64 + nl] = v.z;
            xs[(k + 3) * 64 + nl] = v.w;
        }
    } else {
#pragma unroll
        for (int kk = 0; kk < 32; ++kk) xs[(q * 32 + kk) * 64 + nl] = 0.f;
    }
    __syncthreads();

    // ---- stage 1+2: this wave's 64 hu values, 8 at a time ----
    float acc2[16];
#pragma unroll
    for (int j = 0; j < 16; ++j) acc2[j] = 0.f;
    for (int hh = 0; hh < 64; hh += 8) {
        const int hu0 = q * 64 + hh;
        const float* wb = W1 + (size_t)hu0 * 128;
        float a[8];
#pragma unroll
        for (int r = 0; r < 8; ++r) a[r] = 0.f;
        for (int k = 0; k < 128; ++k) {
            float xv = xs[k * 64 + nl];
#pragma unroll
            for (int r = 0; r < 8; ++r) a[r] = fmaf(wb[r * 128 + k], xv, a[r]);
        }
#pragma unroll
        for (int r = 0; r < 8; ++r) {
            float h1 = lrelu(a[r] + b1[hu0 + r]);
#pragma unroll
            for (int j = 0; j < 16; ++j)
                acc2[j] = fmaf(W2[j * 256 + hu0 + r], h1, acc2[j]);
        }
    }
#pragma unroll
    for (int j = 0; j < 16; ++j) part[(q * 64 + nl) * 17 + j] = acc2[j];
    __syncthreads();

    // ---- h2 = lrelu(sum over quarters + b2) -> reuse xs as h2s[n*17+j] ----
    {
        const int j0 = q * 4;
#pragma unroll
        for (int jj = 0; jj < 4; ++jj) {
            int j = j0 + jj;
            float s = b2[j];
#pragma unroll
            for (int qq = 0; qq < 4; ++qq) s += part[(qq * 64 + nl) * 17 + j];
            xs[nl * 17 + j] = lrelu(s);
        }
    }
    __syncthreads();

    // ---- stage 3: o = h2 @ Wn1^T, scaled by dis ----
    {
        const int c0 = q * 4;
        float o[4];
#pragma unroll
        for (int cc = 0; cc < 4; ++cc) {
            float s = 0.f;
#pragma unroll
            for (int j = 0; j < 16; ++j)
                s = fmaf(Wn1[(c0 + cc) * 16 + j], xs[nl * 17 + j], s);
            o[cc] = s;
        }
        if (node < N) {
            float d = dis[node];
            float4* xo = (float4*)(xl + (size_t)node * 16 + c0);
            *xo = make_float4(d * o[0], d * o[1], d * o[2], d * o[3]);
        }
    }
}

// ---------------------------------------------------------------------------
// Gather layer 1 (wave per node, 4 edges x 16 channels in flight):
// inner = xinS[n] + sum_e xinS[srcs[e]];  agg = bias + dis[n]*inner
// xoutS = dis[n] * (leaky(agg) @ Wn2^T)
// ---------------------------------------------------------------------------
__global__ void gather1_k(const int* __restrict__ off, const int* __restrict__ srcs,
                          const float* __restrict__ dis, const float* __restrict__ xin,
                          const float* __restrict__ bias, const float* __restrict__ Wn2,
                          float* __restrict__ xout, int N) {
    __shared__ float w[256];             // transposed: w[j*16+c] = Wn2[c*16+j]
    {
        int j = threadIdx.x >> 4, c = threadIdx.x & 15;
        w[threadIdx.x] = Wn2[c * 16 + j];
    }
    __syncthreads();
    int t = blockIdx.x * 256 + threadIdx.x;
    int n = t >> 6;
    if (n >= N) return;
    int lane = t & 63, sub = lane >> 4, c = lane & 15;
    float acc = (sub == 0) ? xin[(size_t)n * 16 + c] : 0.f;   // self term
    int e1 = off[n + 1];
    for (int e = off[n] + sub; e < e1; e += 4)
        acc += xin[(size_t)srcs[e] * 16 + c];
    acc += __shfl_xor(acc, 16);
    acc += __shfl_xor(acc, 32);
    float d = dis[n];
    float h = lrelu(fmaf(d, acc, bias[c]));
    float o = 0.f;
#pragma unroll
    for (int j = 0; j < 16; ++j) o = fmaf(w[j * 16 + c], __shfl(h, j, 16), o);
    if (sub == 0) xout[(size_t)n * 16 + c] = d * o;
}

// ---------------------------------------------------------------------------
// Gather layer 2 + final projection: out[n] = bsum + sum_c wsum[c]*leaky(agg_c)
// ---------------------------------------------------------------------------
__global__ void gather2_k(const int* __restrict__ off, const int* __restrict__ srcs,
                          const float* __restrict__ dis, const float* __restrict__ xin,
                          const float* __restrict__ bias, const float* __restrict__ wsum,
                          const float* __restrict__ bsum, float* __restrict__ out, int N) {
    int t = blockIdx.x * 256 + threadIdx.x;
    int n = t >> 6;
    if (n >= N) return;
    int lane = t & 63, sub = lane >> 4, c = lane & 15;
    float acc = (sub == 0) ? xin[(size_t)n * 16 + c] : 0.f;
    int e1 = off[n + 1];
    for (int e = off[n] + sub; e < e1; e += 4)
        acc += xin[(size_t)srcs[e] * 16 + c];
    acc += __shfl_xor(acc, 16);
    acc += __shfl_xor(acc, 32);
    float v = wsum[c] * lrelu(fmaf(dis[n], acc, bias[c]));
#pragma unroll
    for (int m = 1; m < 16; m <<= 1) v += __shfl_xor(v, m);
    if (lane == 0) out[n] = v + bsum[0];
}

// ---------------------------------------------------------------------------
extern "C" void kernel_launch(void* const* d_in, const int* in_sizes, int n_in,
                              void* d_out, int out_size, void* d_ws, size_t ws_size,
                              hipStream_t stream) {
    const float* x      = (const float*)d_in[0];
    const int*   edge   = (const int*)d_in[1];
    const float* W1     = (const float*)d_in[2];
    const float* b1     = (const float*)d_in[3];
    const float* W2     = (const float*)d_in[4];
    const float* b2     = (const float*)d_in[5];
    const float* mem1   = (const float*)d_in[6];
    const float* g1_Wih = (const float*)d_in[7];
    const float* g1_bih = (const float*)d_in[9];
    const float* g1_bhh = (const float*)d_in[10];
    const float* wt1_W  = (const float*)d_in[11];
    const float* wt1_b  = (const float*)d_in[12];
    const float* gcn1_b = (const float*)d_in[13];
    const float* mem2   = (const float*)d_in[14];
    const float* g2_Wih = (const float*)d_in[15];
    const float* g2_bih = (const float*)d_in[17];
    const float* g2_bhh = (const float*)d_in[18];
    const float* wt2_W  = (const float*)d_in[19];
    const float* wt2_b  = (const float*)d_in[20];
    const float* gcn2_b = (const float*)d_in[21];
    const float* Wout   = (const float*)d_in[22];
    const float* bout   = (const float*)d_in[23];
    float* out = (float*)d_out;

    const int N = in_sizes[0] / 128;
    const int E = in_sizes[1] / 2;
    const int* row = edge;
    const int* col = edge + E;

    const int gN  = (N + 255) / 256;       // blocks over nodes
    const int gE  = (E + 255) / 256;       // blocks over edges
    const int gM  = (N + 63) / 64;         // mlp blocks (64 nodes each)
    const int gG  = (N * 64 + 255) / 256;  // gather blocks (wave per node)
    const int gF1 = (E + 2047) / 2048;     // fill1 blocks (2048 edges each)
    const int gF2 = (E + 511) / 512;       // fill2 blocks (512 entries each)
    const int NB  = gN;                    // scan block count (<=512)

    float* ws    = (float*)d_ws;
    float* bufA  = ws;                        // [N*16] xl1 (dis-scaled)
    float* bufB  = bufA + (size_t)N * 16;     // [N*16] xl2 (dis-scaled)
    float* dis   = bufB + (size_t)N * 16;     // [N]
    float* sm    = dis + N;                   // smalls
    float* Wn1   = sm;
    float* Wn2   = sm + 256;
    float* wsum  = sm + 512;
    float* bsum  = sm + 528;
    int*   cnt   = (int*)(sm + 544);          // [N]
    int*   off   = cnt + N;                   // [N+1]
    int*   cur   = off + N + 1;               // [N]
    int*   bred  = cur + N;                   // [NB]
    int*   bscan = bred + NB;                 // [NB]
    int*   bcur  = bscan + NB;                // [BMAX]
    int*   srcs  = bcur + BMAX;               // [E]
    // stage: 16B-aligned int2[E]
    size_t stoff = (size_t)(srcs + E - (int*)d_ws);
    stoff = (stoff + 3) & ~(size_t)3;
    int2*  stage = (int2*)((int*)d_ws + stoff);

    prep_k<<<1, 256, 0, stream>>>(mem1, g1_Wih, g1_bih, g1_bhh,
                                  mem2, g2_Wih, g2_bih, g2_bhh,
                                  wt1_W, wt1_b, wt2_W, wt2_b,
                                  Wout, bout, Wn1, Wn2, wsum, bsum);
    zero_k<<<gN, 256, 0, stream>>>(cnt, N);
    hist_k<<<gE, 256, 0, stream>>>(cnt, col, E);
    sred_k<<<gN, 256, 0, stream>>>(cnt, bred, N);
    sscan_k<<<1, 512, 0, stream>>>(bred, bscan, off, NB, N, E);
    sfin_k<<<gN, 256, 0, stream>>>(cnt, bscan, off, cur, dis, bcur, N);
    fill1_k<<<gF1, 256, 0, stream>>>(row, col, cur, bcur, stage, E);
    fill2_k<<<gF2, 256, 0, stream>>>(stage, srcs, E);
    mlp_k<<<gM, 256, 0, stream>>>(x, W1, b1, W2, b2, Wn1, dis, bufA, N);
    gather1_k<<<gG, 256, 0, stream>>>(off, srcs, dis, bufA, gcn1_b, Wn2, bufB, N);
    gather2_k<<<gG, 256, 0, stream>>>(off, srcs, dis, bufB, gcn2_b, wsum, bsum, out, N);
}

// Round 6
// 707.526 us; speedup vs baseline: 3.2272x; 1.1502x over previous
//
#include <hip/hip_runtime.h>
#include <math.h>

#define SLOPE 0.01f
#define BSH  11          // destination bucket = dest >> 11  (2048 dests/bucket)
#define BMAX 64          // max buckets (N <= 131072)

__device__ __forceinline__ float lrelu(float v) { return v >= 0.f ? v : SLOPE * v; }

// ---------------------------------------------------------------------------
// GRU step (h0=0) for both layers, regenerate GCN weights, fold Wout/bout.
// ---------------------------------------------------------------------------
__global__ void prep_k(const float* __restrict__ m1, const float* __restrict__ Wih1,
                       const float* __restrict__ bih1, const float* __restrict__ bhh1,
                       const float* __restrict__ m2, const float* __restrict__ Wih2,
                       const float* __restrict__ bih2, const float* __restrict__ bhh2,
                       const float* __restrict__ wtW1, const float* __restrict__ wtb1,
                       const float* __restrict__ wtW2, const float* __restrict__ wtb2,
                       const float* __restrict__ Wout, const float* __restrict__ bout,
                       float* __restrict__ Wn1, float* __restrict__ Wn2,
                       float* __restrict__ wsum, float* __restrict__ bsum) {
    __shared__ float nm[32];   // new_mem1 [0..15], new_mem2 [16..31]
    int t = threadIdx.x;
    if (t < 32) {
        int L = t >> 4, j = t & 15;
        const float* m   = L ? m2   : m1;
        const float* Wih = L ? Wih2 : Wih1;
        const float* bih = L ? bih2 : bih1;
        const float* bhh = L ? bhh2 : bhh1;
        float gr = bih[j], gz = bih[16 + j], gn = bih[32 + j];
        for (int k = 0; k < 16; ++k) {
            float mk = m[k];
            gr += Wih[j * 16 + k] * mk;
            gz += Wih[(16 + j) * 16 + k] * mk;
            gn += Wih[(32 + j) * 16 + k] * mk;
        }
        float r = 1.f / (1.f + expf(-(gr + bhh[j])));
        float z = 1.f / (1.f + expf(-(gz + bhh[16 + j])));
        float n = tanhf(gn + r * bhh[32 + j]);
        nm[t] = (1.f - z) * n;          // + z*h, h==0
    }
    __syncthreads();
    float s1 = wtb1[t], s2 = wtb2[t];
    for (int k = 0; k < 16; ++k) {
        s1 += wtW1[t * 16 + k] * nm[k];
        s2 += wtW2[t * 16 + k] * nm[16 + k];
    }
    Wn1[t] = s1;
    Wn2[t] = s2;
    if (t < 16) wsum[t] = Wout[t] + Wout[16 + t];
    if (t == 0) bsum[0] = bout[0] + bout[1];
}

// ---------------------------------------------------------------------------
// CSR build: zero -> histogram(+rank) -> 3-pass scan -> bucketed 2-pass fill
// ---------------------------------------------------------------------------
__global__ void zero_k(int* __restrict__ cnt, int N) {
    int i = blockIdx.x * 256 + threadIdx.x;
    if (i < N) cnt[i] = 0;
}

// histogram; also records each edge's rank within its destination row so
// fill1 needs no device atomics (pos = off[col] + rank).
__global__ void hist_k(int* __restrict__ cnt, const int* __restrict__ col,
                       int* __restrict__ rank, int E) {
    int e = blockIdx.x * 256 + threadIdx.x;
    if (e < E) rank[e] = atomicAdd(cnt + col[e], 1);
}

// pass A: per-block sum of 256 counts
__global__ void sred_k(const int* __restrict__ cnt, int* __restrict__ bred, int N) {
    __shared__ int s[4];
    int i = blockIdx.x * 256 + threadIdx.x;
    int v = (i < N) ? cnt[i] : 0;
#pragma unroll
    for (int m = 1; m < 64; m <<= 1) v += __shfl_xor(v, m);
    if ((threadIdx.x & 63) == 0) s[threadIdx.x >> 6] = v;
    __syncthreads();
    if (threadIdx.x == 0) bred[blockIdx.x] = s[0] + s[1] + s[2] + s[3];
}

// pass B: single-block exclusive scan of block sums (NB <= 512)
__global__ __launch_bounds__(512) void sscan_k(const int* __restrict__ bred,
                                               int* __restrict__ bscan,
                                               int* __restrict__ off,
                                               int NB, int N, int E) {
    __shared__ int s[512];
    int t = threadIdx.x;
    int v = (t < NB) ? bred[t] : 0;
    s[t] = v;
    __syncthreads();
    for (int d = 1; d < 512; d <<= 1) {
        int u = (t >= d) ? s[t - d] : 0;
        __syncthreads();
        s[t] += u;
        __syncthreads();
    }
    if (t < NB) bscan[t] = s[t] - v;   // exclusive
    if (t == 0) off[N] = E;
}

// pass C: per-block exclusive scan + apply; also dis and bucket bases
__global__ void sfin_k(const int* __restrict__ cnt, const int* __restrict__ bscan,
                       int* __restrict__ off, float* __restrict__ dis,
                       int* __restrict__ bcur, int N) {
    __shared__ int s[256];
    int t = threadIdx.x;
    int i = blockIdx.x * 256 + t;
    int v = (i < N) ? cnt[i] : 0;
    s[t] = v;
    __syncthreads();
    for (int d = 1; d < 256; d <<= 1) {
        int u = (t >= d) ? s[t - d] : 0;
        __syncthreads();
        s[t] += u;
        __syncthreads();
    }
    int ex = s[t] - v + bscan[blockIdx.x];
    if (i < N) {
        off[i] = ex;
        dis[i] = rsqrtf((float)(v + 1));   // in-degree + self-loop
        if ((i & ((1 << BSH) - 1)) == 0) bcur[i >> BSH] = ex;  // bucket base
    }
}

// fill pass 1: per-block LDS bucket counts -> chunk reservation -> dense
// append of (src,pos) into bucket-ordered stage. pos = off[dest] + rank[e]
// (no device atomics here; rank came from hist_k).
__global__ void fill1_k(const int* __restrict__ row, const int* __restrict__ col,
                        const int* __restrict__ rank, const int* __restrict__ off,
                        int* __restrict__ bcur, int2* __restrict__ stage, int E) {
    __shared__ int lcnt[BMAX];
    __shared__ int lbase[BMAX];
    const int t = threadIdx.x;
    if (t < BMAX) lcnt[t] = 0;
    __syncthreads();
    const int base = blockIdx.x * 2048;
    int r[8], pos[8], pk[8];
#pragma unroll
    for (int i = 0; i < 8; ++i) {
        int e = base + i * 256 + t;
        if (e < E) {
            int d = col[e];
            int b = d >> BSH;
            int slot = atomicAdd(&lcnt[b], 1);
            r[i]   = row[e];
            pos[i] = off[d] + rank[e];
            pk[i]  = (b << 16) | slot;
        } else pk[i] = -1;
    }
    __syncthreads();
    if (t < BMAX) lbase[t] = atomicAdd(bcur + t, lcnt[t]);
    __syncthreads();
#pragma unroll
    for (int i = 0; i < 8; ++i) {
        if (pk[i] >= 0) {
            int b = pk[i] >> 16, slot = pk[i] & 0xFFFF;
            stage[lbase[b] + slot] = make_int2(r[i], pos[i]);
        }
    }
}

// fill pass 2: stream stage coalesced, scatter into per-bucket srcs windows
__global__ void fill2_k(const int2* __restrict__ stage, int* __restrict__ srcs, int E) {
    int i0 = (blockIdx.x * 256 + threadIdx.x) * 2;
    if (i0 + 1 < E) {
        int4 v = *(const int4*)(stage + i0);   // 16B load (stage 16B-aligned)
        srcs[v.y] = v.x;
        srcs[v.w] = v.z;
    } else if (i0 < E) {
        int2 v = stage[i0];
        srcs[v.y] = v.x;
    }
}

// ---------------------------------------------------------------------------
// Fused MLP: xl1S = dis * (leaky(leaky(x@W1^T+b1)@W2^T+b2) @ Wn1^T)
// 64 nodes/block; 4 waves own 64-hu quarters; W1/W2 wave-uniform -> s_load.
// LDS: single 32 KB buffer; part/h2s overlay the xs region after a barrier
// (49 KB -> 32 KB: 3 -> 5 blocks/CU). Inner loop kept simple (1 ds_read +
// 8 FMA per k) -- the R3 register-batched variant spilled to scratch.
// ---------------------------------------------------------------------------
__global__ __launch_bounds__(256, 5) void mlp_k(
        const float* __restrict__ x, const float* __restrict__ W1,
        const float* __restrict__ b1, const float* __restrict__ W2,
        const float* __restrict__ b2, const float* __restrict__ Wn1,
        const float* __restrict__ dis, float* __restrict__ xl, int N) {
    __shared__ float buf[128 * 64];      // 32 KB
    float* xs   = buf;                   // [k*64+n]      while x tile live
    float* part = buf;                   // [(q*64+n)*17+j]  after barrier
    float* h2s  = buf + 4 * 64 * 17;     // [n*17+j]
    const int t    = threadIdx.x;
    const int nl   = t & 63;
    const int q    = __builtin_amdgcn_readfirstlane(t >> 6);  // wave-uniform
    const int node = blockIdx.x * 64 + nl;

    // ---- stage x tile (transposed, conflict-free) ----
    if (node < N) {
        const float4* xr = (const float4*)(x + (size_t)node * 128) + q * 8;
#pragma unroll
        for (int kk = 0; kk < 8; ++kk) {
            float4 v = xr[kk];
            int k = q * 32 + kk * 4;
            xs[(k + 0) * 64 + nl] = v.x;
            xs[(k + 1) * 64 + nl] = v.y;
            xs[(k + 2) * 64 + nl] = v.z;
            xs[(k + 3) * 64 + nl] = v.w;
        }
    } else {
#pragma unroll
        for (int kk = 0; kk < 32; ++kk) xs[(q * 32 + kk) * 64 + nl] = 0.f;
    }
    __syncthreads();

    // ---- stage 1+2: this wave's 64 hu values, 8 at a time ----
    float acc2[16];
#pragma unroll
    for (int j = 0; j < 16; ++j) acc2[j] = 0.f;
    for (int hh = 0; hh < 64; hh += 8) {
        const int hu0 = q * 64 + hh;
        const float* wb = W1 + (size_t)hu0 * 128;
        float a[8];
#pragma unroll
        for (int r = 0; r < 8; ++r) a[r] = 0.f;
        for (int k = 0; k < 128; ++k) {
            float xv = xs[k * 64 + nl];
#pragma unroll
            for (int r = 0; r < 8; ++r) a[r] = fmaf(wb[r * 128 + k], xv, a[r]);
        }
#pragma unroll
        for (int r = 0; r < 8; ++r) {
            float h1 = lrelu(a[r] + b1[hu0 + r]);
#pragma unroll
            for (int j = 0; j < 16; ++j)
                acc2[j] = fmaf(W2[j * 256 + hu0 + r], h1, acc2[j]);
        }
    }
    __syncthreads();   // everyone done reading xs; safe to overlay part
#pragma unroll
    for (int j = 0; j < 16; ++j) part[(q * 64 + nl) * 17 + j] = acc2[j];
    __syncthreads();

    // ---- h2 = lrelu(sum over quarters + b2) -> h2s (behind part region) ----
    {
        const int j0 = q * 4;
#pragma unroll
        for (int jj = 0; jj < 4; ++jj) {
            int j = j0 + jj;
            float s = b2[j];
#pragma unroll
            for (int qq = 0; qq < 4; ++qq) s += part[(qq * 64 + nl) * 17 + j];
            h2s[nl * 17 + j] = lrelu(s);
        }
    }
    __syncthreads();

    // ---- stage 3: o = h2 @ Wn1^T, scaled by dis ----
    {
        const int c0 = q * 4;
        float o[4];
#pragma unroll
        for (int cc = 0; cc < 4; ++cc) {
            float s = 0.f;
#pragma unroll
            for (int j = 0; j < 16; ++j)
                s = fmaf(Wn1[(c0 + cc) * 16 + j], h2s[nl * 17 + j], s);
            o[cc] = s;
        }
        if (node < N) {
            float d = dis[node];
            float4* xo = (float4*)(xl + (size_t)node * 16 + c0);
            *xo = make_float4(d * o[0], d * o[1], d * o[2], d * o[3]);
        }
    }
}

// ---------------------------------------------------------------------------
// Gather layer 1 (wave per node, 4 edges x 16 channels in flight):
// inner = xinS[n] + sum_e xinS[srcs[e]];  agg = bias + dis[n]*inner
// xoutS = dis[n] * (leaky(agg) @ Wn2^T)
// ---------------------------------------------------------------------------
__global__ void gather1_k(const int* __restrict__ off, const int* __restrict__ srcs,
                          const float* __restrict__ dis, const float* __restrict__ xin,
                          const float* __restrict__ bias, const float* __restrict__ Wn2,
                          float* __restrict__ xout, int N) {
    __shared__ float w[256];             // transposed: w[j*16+c] = Wn2[c*16+j]
    {
        int j = threadIdx.x >> 4, c = threadIdx.x & 15;
        w[threadIdx.x] = Wn2[c * 16 + j];
    }
    __syncthreads();
    int t = blockIdx.x * 256 + threadIdx.x;
    int n = t >> 6;
    if (n >= N) return;
    int lane = t & 63, sub = lane >> 4, c = lane & 15;
    float acc = (sub == 0) ? xin[(size_t)n * 16 + c] : 0.f;   // self term
    int e1 = off[n + 1];
    for (int e = off[n] + sub; e < e1; e += 4)
        acc += xin[(size_t)srcs[e] * 16 + c];
    acc += __shfl_xor(acc, 16);
    acc += __shfl_xor(acc, 32);
    float d = dis[n];
    float h = lrelu(fmaf(d, acc, bias[c]));
    float o = 0.f;
#pragma unroll
    for (int j = 0; j < 16; ++j) o = fmaf(w[j * 16 + c], __shfl(h, j, 16), o);
    if (sub == 0) xout[(size_t)n * 16 + c] = d * o;
}

// ---------------------------------------------------------------------------
// Gather layer 2 + final projection: out[n] = bsum + sum_c wsum[c]*leaky(agg_c)
// ---------------------------------------------------------------------------
__global__ void gather2_k(const int* __restrict__ off, const int* __restrict__ srcs,
                          const float* __restrict__ dis, const float* __restrict__ xin,
                          const float* __restrict__ bias, const float* __restrict__ wsum,
                          const float* __restrict__ bsum, float* __restrict__ out, int N) {
    int t = blockIdx.x * 256 + threadIdx.x;
    int n = t >> 6;
    if (n >= N) return;
    int lane = t & 63, sub = lane >> 4, c = lane & 15;
    float acc = (sub == 0) ? xin[(size_t)n * 16 + c] : 0.f;
    int e1 = off[n + 1];
    for (int e = off[n] + sub; e < e1; e += 4)
        acc += xin[(size_t)srcs[e] * 16 + c];
    acc += __shfl_xor(acc, 16);
    acc += __shfl_xor(acc, 32);
    float v = wsum[c] * lrelu(fmaf(dis[n], acc, bias[c]));
#pragma unroll
    for (int m = 1; m < 16; m <<= 1) v += __shfl_xor(v, m);
    if (lane == 0) out[n] = v + bsum[0];
}

// ---------------------------------------------------------------------------
extern "C" void kernel_launch(void* const* d_in, const int* in_sizes, int n_in,
                              void* d_out, int out_size, void* d_ws, size_t ws_size,
                              hipStream_t stream) {
    const float* x      = (const float*)d_in[0];
    const int*   edge   = (const int*)d_in[1];
    const float* W1     = (const float*)d_in[2];
    const float* b1     = (const float*)d_in[3];
    const float* W2     = (const float*)d_in[4];
    const float* b2     = (const float*)d_in[5];
    const float* mem1   = (const float*)d_in[6];
    const float* g1_Wih = (const float*)d_in[7];
    const float* g1_bih = (const float*)d_in[9];
    const float* g1_bhh = (const float*)d_in[10];
    const float* wt1_W  = (const float*)d_in[11];
    const float* wt1_b  = (const float*)d_in[12];
    const float* gcn1_b = (const float*)d_in[13];
    const float* mem2   = (const float*)d_in[14];
    const float* g2_Wih = (const float*)d_in[15];
    const float* g2_bih = (const float*)d_in[17];
    const float* g2_bhh = (const float*)d_in[18];
    const float* wt2_W  = (const float*)d_in[19];
    const float* wt2_b  = (const float*)d_in[20];
    const float* gcn2_b = (const float*)d_in[21];
    const float* Wout   = (const float*)d_in[22];
    const float* bout   = (const float*)d_in[23];
    float* out = (float*)d_out;

    const int N = in_sizes[0] / 128;
    const int E = in_sizes[1] / 2;
    const int* row = edge;
    const int* col = edge + E;

    const int gN  = (N + 255) / 256;       // blocks over nodes
    const int gE  = (E + 255) / 256;       // blocks over edges
    const int gM  = (N + 63) / 64;         // mlp blocks (64 nodes each)
    const int gG  = (N * 64 + 255) / 256;  // gather blocks (wave per node)
    const int gF1 = (E + 2047) / 2048;     // fill1 blocks (2048 edges each)
    const int gF2 = (E + 511) / 512;       // fill2 blocks (512 entries each)
    const int NB  = gN;                    // scan block count (<=512)

    float* ws    = (float*)d_ws;
    float* bufA  = ws;                        // [N*16] xl1 (dis-scaled)
    float* bufB  = bufA + (size_t)N * 16;     // [N*16] xl2 (dis-scaled)
    float* dis   = bufB + (size_t)N * 16;     // [N]
    float* sm    = dis + N;                   // smalls
    float* Wn1   = sm;
    float* Wn2   = sm + 256;
    float* wsum  = sm + 512;
    float* bsum  = sm + 528;
    int*   cnt   = (int*)(sm + 544);          // [N]
    int*   off   = cnt + N;                   // [N+1]
    int*   rank  = off + N + 1;               // [E]
    int*   bred  = rank + E;                  // [NB]
    int*   bscan = bred + NB;                 // [NB]
    int*   bcur  = bscan + NB;                // [BMAX]
    int*   srcs  = bcur + BMAX;               // [E]
    // stage: 16B-aligned int2[E]
    size_t stoff = (size_t)(srcs + E - (int*)d_ws);
    stoff = (stoff + 3) & ~(size_t)3;
    int2*  stage = (int2*)((int*)d_ws + stoff);

    prep_k<<<1, 256, 0, stream>>>(mem1, g1_Wih, g1_bih, g1_bhh,
                                  mem2, g2_Wih, g2_bih, g2_bhh,
                                  wt1_W, wt1_b, wt2_W, wt2_b,
                                  Wout, bout, Wn1, Wn2, wsum, bsum);
    zero_k<<<gN, 256, 0, stream>>>(cnt, N);
    hist_k<<<gE, 256, 0, stream>>>(cnt, col, rank, E);
    sred_k<<<gN, 256, 0, stream>>>(cnt, bred, N);
    sscan_k<<<1, 512, 0, stream>>>(bred, bscan, off, NB, N, E);
    sfin_k<<<gN, 256, 0, stream>>>(cnt, bscan, off, dis, bcur, N);
    fill1_k<<<gF1, 256, 0, stream>>>(row, col, rank, off, bcur, stage, E);
    fill2_k<<<gF2, 256, 0, stream>>>(stage, srcs, E);
    mlp_k<<<gM, 256, 0, stream>>>(x, W1, b1, W2, b2, Wn1, dis, bufA, N);
    gather1_k<<<gG, 256, 0, stream>>>(off, srcs, dis, bufA, gcn1_b, Wn2, bufB, N);
    gather2_k<<<gG, 256, 0, stream>>>(off, srcs, dis, bufB, gcn2_b, wsum, bsum, out, N);
}